// Round 11
// baseline (8416.203 us; speedup 1.0000x reference)
//
#include <hip/hip_runtime.h>
#include <stdint.h>

// numpy is compiled without fast-math; elementwise ufuncs round mul/add
// separately. Keep hipcc from contracting; dots use explicit fmaf where
// the reference backend (OpenBLAS/einsum-FMA) genuinely fuses.
#pragma clang fp contract(off)

#define B 4096
#define T 64
#define F 128
#define U 256
#define H 256
#define GU 1024   // 4U
#define NJ 32768  // F*H
#define MC 32
#define CH 256    // gibbs/gemm batch chunk
#define BT 32     // lstm batch tile

// ---------------- threefry2x32 (JAX, 20 rounds) ----------------
__host__ __device__ inline void tf2x32(uint32_t k0, uint32_t k1,
                                       uint32_t x0, uint32_t x1,
                                       uint32_t& o0, uint32_t& o1) {
  uint32_t ks2 = k0 ^ k1 ^ 0x1BD11BDAu;
  x0 += k0; x1 += k1;
#define TFR(r) { x0 += x1; x1 = (x1 << r) | (x1 >> (32 - r)); x1 ^= x0; }
  TFR(13) TFR(15) TFR(26) TFR(6)
  x0 += k1;  x1 += ks2 + 1u;
  TFR(17) TFR(29) TFR(16) TFR(24)
  x0 += ks2; x1 += k0 + 2u;
  TFR(13) TFR(15) TFR(26) TFR(6)
  x0 += k0;  x1 += k1 + 3u;
  TFR(17) TFR(29) TFR(16) TFR(24)
  x0 += k1;  x1 += ks2 + 4u;
  TFR(13) TFR(15) TFR(26) TFR(6)
  x0 += ks2; x1 += k0 + 5u;
#undef TFR
  o0 = x0; o1 = x1;
}

// partitionable random_bits(32): block at (hi=0, lo=i), fold o0^o1
__device__ inline uint32_t tf_bits(uint32_t kx, uint32_t ky, uint32_t i) {
  uint32_t o0, o1;
  tf2x32(kx, ky, 0u, i, o0, o1);
  return o0 ^ o1;
}

// exact f32 uniform in [0,1)
__device__ inline float u01_f32(uint32_t bits) {
  return __uint_as_float((bits >> 9) | 0x3F800000u) - 1.0f;
}

// Giles erfinv f32 (jax formula ported to numpy ops: separate mul/add,
// np.log1p ~= libm log1pf)
__device__ inline float erfinv_f32(float x) {
  float w = -log1pf(-(x * x));
  float p;
  if (w < 5.0f) {
    float ww = w - 2.5f;
    p = 2.81022636e-08f;
    p = p * ww + 3.43273939e-07f;
    p = p * ww + (-3.5233877e-06f);
    p = p * ww + (-4.39150654e-06f);
    p = p * ww + 0.00021858087f;
    p = p * ww + (-0.00125372503f);
    p = p * ww + (-0.00417768164f);
    p = p * ww + 0.246640727f;
    p = p * ww + 1.50140941f;
  } else {
    float ww = sqrtf(w) - 3.0f;
    p = -0.000200214257f;
    p = p * ww + 0.000100950558f;
    p = p * ww + 0.00134934322f;
    p = p * ww + (-0.00367342844f);
    p = p * ww + 0.00573950773f;
    p = p * ww + (-0.0076224613f);
    p = p * ww + 0.00943887047f;
    p = p * ww + 1.00167406f;
    p = p * ww + 2.83297682f;
  }
  return p * x;
}

// f32 JAX normal: u = max(lo, u01*2 + lo); sqrt(2,f32) * erfinv(u)
__device__ inline float normal_f32(uint32_t kx, uint32_t ky, uint32_t i) {
  float f = u01_f32(tf_bits(kx, ky, i));
  const float lo = -0.99999994039535522461f;
  float v = f * 2.0f + lo;
  v = fmaxf(lo, v);
  return 1.4142135623730951f * erfinv_f32(v);
}

// np port of jax.nn.sigmoid: 1/(1 + np.exp(-x))
__device__ inline float sigmoid_f32(float x) {
  return 1.0f / (1.0f + expf(-x));
}
// np.logaddexp(x, 0) = max(x,0) + log1p(exp(-|x|))
__device__ inline float softplus_f32(float x) {
  return fmaxf(x, 0.0f) + log1pf(expf(-fabsf(x)));
}

// ---------------- prep kernels: k4-major float4 weight views ----------------
__global__ void prep_lstm_w_k(const float* __restrict__ W_ih, const float* __restrict__ W_hh,
                              const float* __restrict__ b_ih, const float* __restrict__ b_hh,
                              float4* __restrict__ w4t, float* __restrict__ biasg) {
  int idx = blockIdx.x * 256 + threadIdx.x;  // j*96 + k4
  if (idx < GU * 96) {
    int j = idx / 96, k4 = idx - j * 96;
    float v[4];
#pragma unroll
    for (int m = 0; m < 4; ++m) {
      int k = k4 * 4 + m;
      v[m] = (k < F) ? W_ih[(size_t)j * F + k] : W_hh[(size_t)j * U + (k - F)];
    }
    w4t[(size_t)k4 * GU + j] = make_float4(v[0], v[1], v[2], v[3]);
  }
  if (idx < GU) biasg[idx] = b_ih[idx] + b_hh[idx];
}

__global__ void prep_wts_k(const float* __restrict__ wts_W, float4* __restrict__ wts4t) {
  int idx = blockIdx.x * 256 + threadIdx.x;  // j*64 + k4
  if (idx >= NJ * 64) return;
  int j = idx >> 6, k4 = idx & 63;
  const float* r = wts_W + (size_t)j * U + k4 * 4;
  wts4t[(size_t)k4 * NJ + j] = make_float4(r[0], r[1], r[2], r[3]);
}

__global__ void prep_bp_k(const float* __restrict__ bias_W, const float* __restrict__ prec_W,
                          float4* __restrict__ bp4t) {
  int idx = blockIdx.x * 256 + threadIdx.x;  // j*64 + k4, j<256
  if (idx >= 256 * 64) return;
  int j = idx >> 6, k4 = idx & 63;
  const float* r = (j < F) ? (bias_W + (size_t)j * U + k4 * 4)
                           : (prec_W + (size_t)(j - F) * U + k4 * 4);
  bp4t[(size_t)k4 * 256 + j] = make_float4(r[0], r[1], r[2], r[3]);
}

// ---------------- LSTM step f32: OpenBLAS-style k-seq FMA dots --------------
// g = (x@Wih.T + h@Whh.T) + bias; gates with exp-sigmoid + libm tanh.
__global__ __launch_bounds__(256) void lstm_step_k(
    const float* __restrict__ x, const float* __restrict__ h_in,
    const float* __restrict__ c_in, const float4* __restrict__ w4t,
    const float* __restrict__ biasg, float* __restrict__ h_out,
    float* __restrict__ c_out, int t) {
  __shared__ float xt[BT * 128];   // 16 KB
  __shared__ float ht[BT * 256];   // 32 KB
  const int tid = threadIdx.x;
  const int b0 = blockIdx.x * BT;
  const int ut = blockIdx.y;       // 0..3
  for (int q = tid; q < BT * 32; q += 256) {
    int row = q >> 5, c4 = q & 31;
    *(float4*)(xt + row * 128 + c4 * 4) =
        *(const float4*)(x + ((size_t)(b0 + row) * T + t) * F + c4 * 4);
  }
  for (int q = tid; q < BT * 64; q += 256) {
    int row = q >> 6, c4 = q & 63;
    *(float4*)(ht + row * 256 + c4 * 4) =
        *(const float4*)(h_in + (size_t)(b0 + row) * U + c4 * 4);
  }
  __syncthreads();
  const int u_loc = tid & 63, bg = tid >> 6;
  const int u = ut * 64 + u_loc;
  float accX[4][8], accH[4][8];
#pragma unroll
  for (int g = 0; g < 4; ++g)
#pragma unroll
    for (int b = 0; b < 8; ++b) { accX[g][b] = 0.0f; accH[g][b] = 0.0f; }

  for (int k4 = 0; k4 < 32; ++k4) {  // x-dot, k-sequential fmaf
    float4 wf[4];
#pragma unroll
    for (int g = 0; g < 4; ++g) wf[g] = w4t[(size_t)k4 * GU + g * U + u];
#pragma unroll
    for (int b = 0; b < 8; ++b) {
      const float* ap = xt + (bg * 8 + b) * 128 + k4 * 4;
      float a0 = ap[0], a1 = ap[1], a2 = ap[2], a3 = ap[3];
#pragma unroll
      for (int g = 0; g < 4; ++g) {
        accX[g][b] = fmaf(a0, wf[g].x, accX[g][b]);
        accX[g][b] = fmaf(a1, wf[g].y, accX[g][b]);
        accX[g][b] = fmaf(a2, wf[g].z, accX[g][b]);
        accX[g][b] = fmaf(a3, wf[g].w, accX[g][b]);
      }
    }
  }
  for (int k4 = 32; k4 < 96; ++k4) {  // h-dot, k-sequential fmaf
    float4 wf[4];
#pragma unroll
    for (int g = 0; g < 4; ++g) wf[g] = w4t[(size_t)k4 * GU + g * U + u];
#pragma unroll
    for (int b = 0; b < 8; ++b) {
      const float* ap = ht + (bg * 8 + b) * 256 + (k4 - 32) * 4;
      float a0 = ap[0], a1 = ap[1], a2 = ap[2], a3 = ap[3];
#pragma unroll
      for (int g = 0; g < 4; ++g) {
        accH[g][b] = fmaf(a0, wf[g].x, accH[g][b]);
        accH[g][b] = fmaf(a1, wf[g].y, accH[g][b]);
        accH[g][b] = fmaf(a2, wf[g].z, accH[g][b]);
        accH[g][b] = fmaf(a3, wf[g].w, accH[g][b]);
      }
    }
  }
  float bi = biasg[u], bf = biasg[U + u], bgg = biasg[2 * U + u], bo = biasg[3 * U + u];
#pragma unroll
  for (int b = 0; b < 8; ++b) {
    size_t gi = (size_t)(b0 + bg * 8 + b) * U + u;
    float c = c_in[gi];
    float g_i = (accX[0][b] + accH[0][b]) + bi;
    float g_f = (accX[1][b] + accH[1][b]) + bf;
    float g_g = (accX[2][b] + accH[2][b]) + bgg;
    float g_o = (accX[3][b] + accH[3][b]) + bo;
    float t1 = sigmoid_f32(g_f) * c;
    float t2 = sigmoid_f32(g_i) * tanhf(g_g);
    float cn = t1 + t2;
    float hn = sigmoid_f32(g_o) * tanhf(cn);
    c_out[gi] = cn;
    h_out[gi] = hn;
  }
}

// ---------------- weights-head GEMM f32, k-seq fmaf (CH rows) ---------------
__global__ __launch_bounds__(256) void gemm_xh_k(
    const float* __restrict__ xh_c, const float4* __restrict__ wts4t,
    const float* __restrict__ wts_b, float* __restrict__ outp) {
  __shared__ float xl[64 * 256];  // 64 KB
  const int tid = threadIdx.x;
  const int b0 = blockIdx.x * 64;
  const int j = blockIdx.y * 256 + tid;
  for (int q = tid; q < 64 * 64; q += 256) {
    int row = q >> 6, c4 = q & 63;
    *(float4*)(xl + row * 256 + c4 * 4) =
        *(const float4*)(xh_c + (size_t)(b0 + row) * U + c4 * 4);
  }
  __syncthreads();
  float acc[64];
#pragma unroll
  for (int b = 0; b < 64; ++b) acc[b] = 0.0f;
  for (int k4 = 0; k4 < 64; ++k4) {
    float4 wf = wts4t[(size_t)k4 * NJ + j];
#pragma unroll
    for (int b = 0; b < 64; ++b) {
      const float* ap = xl + b * 256 + k4 * 4;
      acc[b] = fmaf(ap[0], wf.x, acc[b]);
      acc[b] = fmaf(ap[1], wf.y, acc[b]);
      acc[b] = fmaf(ap[2], wf.z, acc[b]);
      acc[b] = fmaf(ap[3], wf.w, acc[b]);
    }
  }
  float bb = wts_b[j];
#pragma unroll
  for (int b = 0; b < 64; ++b)
    outp[(size_t)(b0 + b) * NJ + j] = acc[b] + bb;
}

// ---------------- bias & precision heads f32 (full batch) -------------------
__global__ __launch_bounds__(256) void biasprec_k(
    const float* __restrict__ xh, const float4* __restrict__ bp4t,
    const float* __restrict__ bias_b, const float* __restrict__ prec_b,
    float* __restrict__ bias_g, float* __restrict__ prec_g) {
  __shared__ float xl[64 * 256];  // 64 KB
  const int tid = threadIdx.x;
  const int b0 = blockIdx.x * 64;
  const int j = tid;
  for (int q = tid; q < 64 * 64; q += 256) {
    int row = q >> 6, c4 = q & 63;
    *(float4*)(xl + row * 256 + c4 * 4) =
        *(const float4*)(xh + (size_t)(b0 + row) * U + c4 * 4);
  }
  __syncthreads();
  float acc[64];
#pragma unroll
  for (int b = 0; b < 64; ++b) acc[b] = 0.0f;
  for (int k4 = 0; k4 < 64; ++k4) {
    float4 wf = bp4t[(size_t)k4 * 256 + j];
#pragma unroll
    for (int b = 0; b < 64; ++b) {
      const float* ap = xl + b * 256 + k4 * 4;
      acc[b] = fmaf(ap[0], wf.x, acc[b]);
      acc[b] = fmaf(ap[1], wf.y, acc[b]);
      acc[b] = fmaf(ap[2], wf.z, acc[b]);
      acc[b] = fmaf(ap[3], wf.w, acc[b]);
    }
  }
  if (j < F) {
    float bb = bias_b[j];
#pragma unroll
    for (int b = 0; b < 64; ++b)
      bias_g[(size_t)(b0 + b) * F + j] = acc[b] + bb;
  } else {
    float pb = prec_b[j - F];
#pragma unroll
    for (int b = 0; b < 64; ++b)
      prec_g[(size_t)(b0 + b) * F + (j - F)] = softplus_f32(acc[b] + pb) + 1e-6f;
  }
}

// ---------------- Gibbs f32: numpy-einsum-order dots ------------------------
struct GKeys {
  uint32_t k0x, k0y;
  uint32_t khx[32], khy[32], kyx[32], kyy[32];
};

__global__ __launch_bounds__(256) void gibbs_k(
    const float* __restrict__ w_g, const float* __restrict__ bias_g,
    const float* __restrict__ prec_g, float* __restrict__ outp, GKeys keys,
    int base) {
  __shared__ float wl[32768];        // [f][j^(f&31)], 128 KB
  __shared__ float yv[128];
  __shared__ float hv[256];
  __shared__ float bs[128];
  __shared__ float ps[128];
  __shared__ float ss[128];
  const int tid = threadIdx.x;
  const int bloc = blockIdx.x;
  const int gb = base + bloc;
  const float4* src = (const float4*)(w_g + (size_t)bloc * NJ);
  for (int q = tid; q < NJ / 4; q += 256) {
    float4 v = src[q];
    int f = q >> 6;
    int j4 = (q & 63) * 4;
    int s = f & 31;
    wl[f * 256 + ((j4 + 0) ^ s)] = v.x;
    wl[f * 256 + ((j4 + 1) ^ s)] = v.y;
    wl[f * 256 + ((j4 + 2) ^ s)] = v.z;
    wl[f * 256 + ((j4 + 3) ^ s)] = v.w;
  }
  if (tid < F) {
    float bb = bias_g[(size_t)gb * F + tid];
    float pp = prec_g[(size_t)gb * F + tid];
    bs[tid] = bb; ps[tid] = pp;
    float sd = 1.0f / sqrtf(pp);
    ss[tid] = sd;
    float n = normal_f32(keys.k0x, keys.k0y, (uint32_t)(gb * F + tid));
    float t1 = sd * n;
    yv[tid] = bb + t1;
  }
  __syncthreads();
  for (int s_ = 0; s_ < MC; ++s_) {
    {  // h phase: einsum "bf,bfh->bh" strided inner -> sequential FMA over f
      const int j = tid;
      float acc = 0.0f;
      for (int f = 0; f < F; ++f)
        acc = fmaf(yv[f], wl[f * 256 + (j ^ (f & 31))], acc);
      float p = sigmoid_f32(acc);
      float u = u01_f32(tf_bits(keys.khx[s_], keys.khy[s_], (uint32_t)(gb * H + j)));
      hv[j] = (u < p) ? 1.0f : 0.0f;
    }
    __syncthreads();
    if (tid < F) {
      // mean phase: einsum "bfh,bh->bf" contiguous inner -> numpy npyv AVX2
      // order: 4 accumulators x 8 lanes, FMA; combine (v0+v1)+(v2+v3)
      // lanewise; horizontal sum ((L0+L1)+(L2+L3)) + ((L4+L5)+(L6+L7)).
      const int sw = tid & 31;
      const float* wr = wl + tid * 256;
      float C0[8], C1[8], C2[8], C3[8];
#pragma unroll
      for (int l = 0; l < 8; ++l) { C0[l] = 0.0f; C1[l] = 0.0f; C2[l] = 0.0f; C3[l] = 0.0f; }
      for (int k = 0; k < 8; ++k) {
        int e = k * 32;
#pragma unroll
        for (int l = 0; l < 8; ++l) {
          C0[l] = fmaf(wr[(e + l) ^ sw],      hv[e + l],      C0[l]);
          C1[l] = fmaf(wr[(e + 8 + l) ^ sw],  hv[e + 8 + l],  C1[l]);
          C2[l] = fmaf(wr[(e + 16 + l) ^ sw], hv[e + 16 + l], C2[l]);
          C3[l] = fmaf(wr[(e + 24 + l) ^ sw], hv[e + 24 + l], C3[l]);
        }
      }
      float L[8];
#pragma unroll
      for (int l = 0; l < 8; ++l) L[l] = (C0[l] + C1[l]) + (C2[l] + C3[l]);
      float S = ((L[0] + L[1]) + (L[2] + L[3])) + ((L[4] + L[5]) + (L[6] + L[7]));
      float d = S / ps[tid];
      float mean = bs[tid] + d;
      if (s_ == MC - 1) {
        outp[(size_t)gb * F + tid] = mean;
      } else {
        float n = normal_f32(keys.kyx[s_], keys.kyy[s_], (uint32_t)(gb * F + tid));
        float t1 = ss[tid] * n;
        yv[tid] = mean + t1;
      }
    }
    __syncthreads();
  }
}

// ---------------- launcher ----------------
extern "C" void kernel_launch(void* const* d_in, const int* in_sizes, int n_in,
                              void* d_out, int out_size, void* d_ws, size_t ws_size,
                              hipStream_t stream) {
  const float* x      = (const float*)d_in[0];
  const float* W_ih   = (const float*)d_in[1];
  const float* W_hh   = (const float*)d_in[2];
  const float* b_ih   = (const float*)d_in[3];
  const float* b_hh   = (const float*)d_in[4];
  const float* bias_W = (const float*)d_in[5];
  const float* bias_b = (const float*)d_in[6];
  const float* prec_W = (const float*)d_in[7];
  const float* prec_b = (const float*)d_in[8];
  const float* wts_W  = (const float*)d_in[9];
  const float* wts_b  = (const float*)d_in[10];
  float* out = (float*)d_out;

  // workspace (~90 MB f32)
  float* wsf = (float*)d_ws;
  size_t off = 0;
  float* w_g     = wsf + off; off += (size_t)CH * NJ;     // 8.39M
  float* h_a     = wsf + off; off += (size_t)B * U;
  float* h_b     = wsf + off; off += (size_t)B * U;
  float* c_a     = wsf + off; off += (size_t)B * U;
  float* c_b     = wsf + off; off += (size_t)B * U;
  float* biasg_g = wsf + off; off += (size_t)B * F;
  float* precg_g = wsf + off; off += (size_t)B * F;
  float* w4t     = wsf + off; off += (size_t)96 * GU * 4;
  float* biasg   = wsf + off; off += GU;
  float* wts4t   = wsf + off; off += (size_t)64 * NJ * 4; // 8.39M
  float* bp4t    = wsf + off; off += (size_t)64 * 256 * 4;
  (void)ws_size;

  hipMemsetAsync(h_a, 0, (size_t)B * U * sizeof(float), stream);
  hipMemsetAsync(c_a, 0, (size_t)B * U * sizeof(float), stream);

  prep_lstm_w_k<<<(GU * 96 + 255) / 256, 256, 0, stream>>>(W_ih, W_hh, b_ih, b_hh,
                                                           (float4*)w4t, biasg);
  prep_wts_k<<<(NJ * 64) / 256, 256, 0, stream>>>(wts_W, (float4*)wts4t);
  prep_bp_k<<<(256 * 64) / 256, 256, 0, stream>>>(bias_W, prec_W, (float4*)bp4t);

  const float* hi = h_a; const float* ci = c_a;
  float* ho = h_b; float* co = c_b;
  for (int t = 0; t < T; ++t) {
    lstm_step_k<<<dim3(B / BT, 4), 256, 0, stream>>>(
        x, hi, ci, (const float4*)w4t, biasg, ho, co, t);
    const float* th_ = hi; hi = ho; ho = (float*)th_;
    const float* tc_ = ci; ci = co; co = (float*)tc_;
  }
  const float* xh = hi;  // last hidden state (T even -> h_a)

  biasprec_k<<<dim3(B / 64), 256, 0, stream>>>(xh, (const float4*)bp4t,
                                               bias_b, prec_b, biasg_g, precg_g);

  // host-side key derivation, jax_threefry_partitionable convention:
  // split(key, n)[i] = full threefry block of (hi=0, lo=i) under `key`.
  GKeys keys;
  uint32_t k0x, k0y, l0, l1;
  tf2x32(0u, 1u, 0u, 0u, k0x, k0y);   // k0    = foldlike(key(1), 0)
  tf2x32(0u, 1u, 0u, 1u, l0, l1);     // kloop = foldlike(key(1), 1)
  keys.k0x = k0x; keys.k0y = k0y;
  for (int s = 0; s < 32; ++s) {
    uint32_t ksx, ksy;
    tf2x32(l0, l1, 0u, (uint32_t)s, ksx, ksy);
    tf2x32(ksx, ksy, 0u, 0u, keys.khx[s], keys.khy[s]);
    tf2x32(ksx, ksy, 0u, 1u, keys.kyx[s], keys.kyy[s]);
  }

  for (int c = 0; c < B / CH; ++c) {
    gemm_xh_k<<<dim3(CH / 64, NJ / 256), 256, 0, stream>>>(
        xh + (size_t)c * CH * U, (const float4*)wts4t, wts_b, w_g);
    gibbs_k<<<dim3(CH), 256, 0, stream>>>(w_g, biasg_g, precg_g, out, keys, c * CH);
  }
}

// Round 12
// 7884.267 us; speedup vs baseline: 1.0675x; 1.0675x over previous
//
#include <hip/hip_runtime.h>
#include <stdint.h>

// numpy is compiled without fast-math; elementwise ufuncs round mul/add
// separately. Keep hipcc from contracting; dots use explicit fmaf where
// the reference backend (OpenBLAS/einsum-FMA) genuinely fuses.
#pragma clang fp contract(off)

#define B 4096
#define T 64
#define F 128
#define U 256
#define H 256
#define GU 1024   // 4U
#define NJ 32768  // F*H
#define MC 32
#define CH 256    // gibbs/gemm batch chunk
#define BT 32     // lstm batch tile

// ---------------- threefry2x32 (JAX, 20 rounds) ----------------
__host__ __device__ inline void tf2x32(uint32_t k0, uint32_t k1,
                                       uint32_t x0, uint32_t x1,
                                       uint32_t& o0, uint32_t& o1) {
  uint32_t ks2 = k0 ^ k1 ^ 0x1BD11BDAu;
  x0 += k0; x1 += k1;
#define TFR(r) { x0 += x1; x1 = (x1 << r) | (x1 >> (32 - r)); x1 ^= x0; }
  TFR(13) TFR(15) TFR(26) TFR(6)
  x0 += k1;  x1 += ks2 + 1u;
  TFR(17) TFR(29) TFR(16) TFR(24)
  x0 += ks2; x1 += k0 + 2u;
  TFR(13) TFR(15) TFR(26) TFR(6)
  x0 += k0;  x1 += k1 + 3u;
  TFR(17) TFR(29) TFR(16) TFR(24)
  x0 += k1;  x1 += ks2 + 4u;
  TFR(13) TFR(15) TFR(26) TFR(6)
  x0 += ks2; x1 += k0 + 5u;
#undef TFR
  o0 = x0; o1 = x1;
}

// partitionable random_bits(32): block at (hi=0, lo=i), fold o0^o1
__device__ inline uint32_t tf_bits(uint32_t kx, uint32_t ky, uint32_t i) {
  uint32_t o0, o1;
  tf2x32(kx, ky, 0u, i, o0, o1);
  return o0 ^ o1;
}

// exact f32 uniform in [0,1)
__device__ inline float u01_f32(uint32_t bits) {
  return __uint_as_float((bits >> 9) | 0x3F800000u) - 1.0f;
}

// Giles erfinv f32 (numpy port: separate mul/add, libm log1pf)
__device__ inline float erfinv_f32(float x) {
  float w = -log1pf(-(x * x));
  float p;
  if (w < 5.0f) {
    float ww = w - 2.5f;
    p = 2.81022636e-08f;
    p = p * ww + 3.43273939e-07f;
    p = p * ww + (-3.5233877e-06f);
    p = p * ww + (-4.39150654e-06f);
    p = p * ww + 0.00021858087f;
    p = p * ww + (-0.00125372503f);
    p = p * ww + (-0.00417768164f);
    p = p * ww + 0.246640727f;
    p = p * ww + 1.50140941f;
  } else {
    float ww = sqrtf(w) - 3.0f;
    p = -0.000200214257f;
    p = p * ww + 0.000100950558f;
    p = p * ww + 0.00134934322f;
    p = p * ww + (-0.00367342844f);
    p = p * ww + 0.00573950773f;
    p = p * ww + (-0.0076224613f);
    p = p * ww + 0.00943887047f;
    p = p * ww + 1.00167406f;
    p = p * ww + 2.83297682f;
  }
  return p * x;
}

// f32 JAX normal: u = max(lo, u01*2 + lo); sqrt(2,f32) * erfinv(u)
__device__ inline float normal_f32(uint32_t kx, uint32_t ky, uint32_t i) {
  float f = u01_f32(tf_bits(kx, ky, i));
  const float lo = -0.99999994039535522461f;
  float v = f * 2.0f + lo;
  v = fmaxf(lo, v);
  return 1.4142135623730951f * erfinv_f32(v);
}

// np port of jax.nn.sigmoid: 1/(1 + np.exp(-x))
__device__ inline float sigmoid_f32(float x) {
  return 1.0f / (1.0f + expf(-x));
}
// np.logaddexp(x, 0) = max(x,0) + log1p(exp(-|x|))
__device__ inline float softplus_f32(float x) {
  return fmaxf(x, 0.0f) + log1pf(expf(-fabsf(x)));
}

// ---------------- prep kernels: k4-major float4 weight views ----------------
__global__ void prep_lstm_w_k(const float* __restrict__ W_ih, const float* __restrict__ W_hh,
                              const float* __restrict__ b_ih, const float* __restrict__ b_hh,
                              float4* __restrict__ w4t, float* __restrict__ biasg) {
  int idx = blockIdx.x * 256 + threadIdx.x;  // j*96 + k4
  if (idx < GU * 96) {
    int j = idx / 96, k4 = idx - j * 96;
    float v[4];
#pragma unroll
    for (int m = 0; m < 4; ++m) {
      int k = k4 * 4 + m;
      v[m] = (k < F) ? W_ih[(size_t)j * F + k] : W_hh[(size_t)j * U + (k - F)];
    }
    w4t[(size_t)k4 * GU + j] = make_float4(v[0], v[1], v[2], v[3]);
  }
  if (idx < GU) biasg[idx] = b_ih[idx] + b_hh[idx];
}

__global__ void prep_wts_k(const float* __restrict__ wts_W, float4* __restrict__ wts4t) {
  int idx = blockIdx.x * 256 + threadIdx.x;  // j*64 + k4
  if (idx >= NJ * 64) return;
  int j = idx >> 6, k4 = idx & 63;
  const float* r = wts_W + (size_t)j * U + k4 * 4;
  wts4t[(size_t)k4 * NJ + j] = make_float4(r[0], r[1], r[2], r[3]);
}

__global__ void prep_bp_k(const float* __restrict__ bias_W, const float* __restrict__ prec_W,
                          float4* __restrict__ bp4t) {
  int idx = blockIdx.x * 256 + threadIdx.x;  // j*64 + k4, j<256
  if (idx >= 256 * 64) return;
  int j = idx >> 6, k4 = idx & 63;
  const float* r = (j < F) ? (bias_W + (size_t)j * U + k4 * 4)
                           : (prec_W + (size_t)(j - F) * U + k4 * 4);
  bp4t[(size_t)k4 * 256 + j] = make_float4(r[0], r[1], r[2], r[3]);
}

// ---------------- LSTM step f32: OpenBLAS-style k-seq FMA dots --------------
// g = (x@Wih.T + h@Whh.T) + bias; gates with exp-sigmoid + libm tanh.
// Identical arithmetic to the passing round-11 kernel; A-operand now read as
// one float4 LDS broadcast instead of 4 scalar b32 (4x fewer LDS wave-ops).
__global__ __launch_bounds__(256) void lstm_step_k(
    const float* __restrict__ x, const float* __restrict__ h_in,
    const float* __restrict__ c_in, const float4* __restrict__ w4t,
    const float* __restrict__ biasg, float* __restrict__ h_out,
    float* __restrict__ c_out, int t) {
  __shared__ __align__(16) float xt[BT * 128];   // 16 KB
  __shared__ __align__(16) float ht[BT * 256];   // 32 KB
  const int tid = threadIdx.x;
  const int b0 = blockIdx.x * BT;
  const int ut = blockIdx.y;       // 0..3
  for (int q = tid; q < BT * 32; q += 256) {
    int row = q >> 5, c4 = q & 31;
    *(float4*)(xt + row * 128 + c4 * 4) =
        *(const float4*)(x + ((size_t)(b0 + row) * T + t) * F + c4 * 4);
  }
  for (int q = tid; q < BT * 64; q += 256) {
    int row = q >> 6, c4 = q & 63;
    *(float4*)(ht + row * 256 + c4 * 4) =
        *(const float4*)(h_in + (size_t)(b0 + row) * U + c4 * 4);
  }
  __syncthreads();
  const int u_loc = tid & 63, bg = tid >> 6;
  const int u = ut * 64 + u_loc;
  float accX[4][8], accH[4][8];
#pragma unroll
  for (int g = 0; g < 4; ++g)
#pragma unroll
    for (int b = 0; b < 8; ++b) { accX[g][b] = 0.0f; accH[g][b] = 0.0f; }

#pragma unroll 4
  for (int k4 = 0; k4 < 32; ++k4) {  // x-dot, k-sequential fmaf
    float4 wf[4];
#pragma unroll
    for (int g = 0; g < 4; ++g) wf[g] = w4t[(size_t)k4 * GU + g * U + u];
#pragma unroll
    for (int b = 0; b < 8; ++b) {
      float4 av = *(const float4*)(xt + (bg * 8 + b) * 128 + k4 * 4);
#pragma unroll
      for (int g = 0; g < 4; ++g) {
        accX[g][b] = fmaf(av.x, wf[g].x, accX[g][b]);
        accX[g][b] = fmaf(av.y, wf[g].y, accX[g][b]);
        accX[g][b] = fmaf(av.z, wf[g].z, accX[g][b]);
        accX[g][b] = fmaf(av.w, wf[g].w, accX[g][b]);
      }
    }
  }
#pragma unroll 4
  for (int k4 = 32; k4 < 96; ++k4) {  // h-dot, k-sequential fmaf
    float4 wf[4];
#pragma unroll
    for (int g = 0; g < 4; ++g) wf[g] = w4t[(size_t)k4 * GU + g * U + u];
#pragma unroll
    for (int b = 0; b < 8; ++b) {
      float4 av = *(const float4*)(ht + (bg * 8 + b) * 256 + (k4 - 32) * 4);
#pragma unroll
      for (int g = 0; g < 4; ++g) {
        accH[g][b] = fmaf(av.x, wf[g].x, accH[g][b]);
        accH[g][b] = fmaf(av.y, wf[g].y, accH[g][b]);
        accH[g][b] = fmaf(av.z, wf[g].z, accH[g][b]);
        accH[g][b] = fmaf(av.w, wf[g].w, accH[g][b]);
      }
    }
  }
  float bi = biasg[u], bf = biasg[U + u], bgg = biasg[2 * U + u], bo = biasg[3 * U + u];
#pragma unroll
  for (int b = 0; b < 8; ++b) {
    size_t gi = (size_t)(b0 + bg * 8 + b) * U + u;
    float c = c_in[gi];
    float g_i = (accX[0][b] + accH[0][b]) + bi;
    float g_f = (accX[1][b] + accH[1][b]) + bf;
    float g_g = (accX[2][b] + accH[2][b]) + bgg;
    float g_o = (accX[3][b] + accH[3][b]) + bo;
    float t1 = sigmoid_f32(g_f) * c;
    float t2 = sigmoid_f32(g_i) * tanhf(g_g);
    float cn = t1 + t2;
    float hn = sigmoid_f32(g_o) * tanhf(cn);
    c_out[gi] = cn;
    h_out[gi] = hn;
  }
}

// ---------------- weights-head GEMM f32, k-seq fmaf (CH rows) ---------------
__global__ __launch_bounds__(256) void gemm_xh_k(
    const float* __restrict__ xh_c, const float4* __restrict__ wts4t,
    const float* __restrict__ wts_b, float* __restrict__ outp) {
  __shared__ __align__(16) float xl[64 * 256];  // 64 KB
  const int tid = threadIdx.x;
  const int b0 = blockIdx.x * 64;
  const int j = blockIdx.y * 256 + tid;
  for (int q = tid; q < 64 * 64; q += 256) {
    int row = q >> 6, c4 = q & 63;
    *(float4*)(xl + row * 256 + c4 * 4) =
        *(const float4*)(xh_c + (size_t)(b0 + row) * U + c4 * 4);
  }
  __syncthreads();
  float acc[64];
#pragma unroll
  for (int b = 0; b < 64; ++b) acc[b] = 0.0f;
  for (int k4 = 0; k4 < 64; ++k4) {
    float4 wf = wts4t[(size_t)k4 * NJ + j];
#pragma unroll
    for (int b = 0; b < 64; ++b) {
      float4 av = *(const float4*)(xl + b * 256 + k4 * 4);
      acc[b] = fmaf(av.x, wf.x, acc[b]);
      acc[b] = fmaf(av.y, wf.y, acc[b]);
      acc[b] = fmaf(av.z, wf.z, acc[b]);
      acc[b] = fmaf(av.w, wf.w, acc[b]);
    }
  }
  float bb = wts_b[j];
#pragma unroll
  for (int b = 0; b < 64; ++b)
    outp[(size_t)(b0 + b) * NJ + j] = acc[b] + bb;
}

// ---------------- bias & precision heads f32 (full batch) -------------------
__global__ __launch_bounds__(256) void biasprec_k(
    const float* __restrict__ xh, const float4* __restrict__ bp4t,
    const float* __restrict__ bias_b, const float* __restrict__ prec_b,
    float* __restrict__ bias_g, float* __restrict__ prec_g) {
  __shared__ __align__(16) float xl[64 * 256];  // 64 KB
  const int tid = threadIdx.x;
  const int b0 = blockIdx.x * 64;
  const int j = tid;
  for (int q = tid; q < 64 * 64; q += 256) {
    int row = q >> 6, c4 = q & 63;
    *(float4*)(xl + row * 256 + c4 * 4) =
        *(const float4*)(xh + (size_t)(b0 + row) * U + c4 * 4);
  }
  __syncthreads();
  float acc[64];
#pragma unroll
  for (int b = 0; b < 64; ++b) acc[b] = 0.0f;
  for (int k4 = 0; k4 < 64; ++k4) {
    float4 wf = bp4t[(size_t)k4 * 256 + j];
#pragma unroll
    for (int b = 0; b < 64; ++b) {
      float4 av = *(const float4*)(xl + b * 256 + k4 * 4);
      acc[b] = fmaf(av.x, wf.x, acc[b]);
      acc[b] = fmaf(av.y, wf.y, acc[b]);
      acc[b] = fmaf(av.z, wf.z, acc[b]);
      acc[b] = fmaf(av.w, wf.w, acc[b]);
    }
  }
  if (j < F) {
    float bb = bias_b[j];
#pragma unroll
    for (int b = 0; b < 64; ++b)
      bias_g[(size_t)(b0 + b) * F + j] = acc[b] + bb;
  } else {
    float pb = prec_b[j - F];
#pragma unroll
    for (int b = 0; b < 64; ++b)
      prec_g[(size_t)(b0 + b) * F + (j - F)] = softplus_f32(acc[b] + pb) + 1e-6f;
  }
}

// ---------------- Gibbs f32: quad-swizzled LDS, vectorized loads ------------
// Layout: element (f, j) at float-index f*256 + ((j>>2) ^ (f&7))*4 + (j&3).
// - staging: float4 stores, conflict-free (8 lanes/bank-group = structural).
// - h-phase: scalar reads, 2-way bank aliasing (free); yv batched per 4 f.
// - mean phase: float4 reads of w and hv; npyv AVX2 tree order preserved.
struct GKeys {
  uint32_t k0x, k0y;
  uint32_t khx[32], khy[32], kyx[32], kyy[32];
};

__global__ __launch_bounds__(256) void gibbs_k(
    const float* __restrict__ w_g, const float* __restrict__ bias_g,
    const float* __restrict__ prec_g, float* __restrict__ outp, GKeys keys,
    int base) {
  __shared__ __align__(16) float wl[32768];   // 128 KB
  __shared__ __align__(16) float yv[128];
  __shared__ __align__(16) float hv[256];
  __shared__ float bs[128];
  __shared__ float ps[128];
  __shared__ float ss[128];
  const int tid = threadIdx.x;
  const int bloc = blockIdx.x;
  const int gb = base + bloc;
  const float4* src = (const float4*)(w_g + (size_t)bloc * NJ);
  float4* wl4 = (float4*)wl;
  for (int q = tid; q < NJ / 4; q += 256) {
    int f = q >> 6;
    int j4 = q & 63;
    wl4[f * 64 + (j4 ^ (f & 7))] = src[q];
  }
  if (tid < F) {
    float bb = bias_g[(size_t)gb * F + tid];
    float pp = prec_g[(size_t)gb * F + tid];
    bs[tid] = bb; ps[tid] = pp;
    float sd = 1.0f / sqrtf(pp);
    ss[tid] = sd;
    float n = normal_f32(keys.k0x, keys.k0y, (uint32_t)(gb * F + tid));
    float t1 = sd * n;
    yv[tid] = bb + t1;
  }
  __syncthreads();
  for (int s_ = 0; s_ < MC; ++s_) {
    {  // h phase: einsum "bf,bfh->bh" -> sequential FMA over f (order fixed)
      const int j = tid;
      const int jq = j >> 2, jm = j & 3;
      // RNG first: independent of the serial dot chain, overlaps its latency
      float u = u01_f32(tf_bits(keys.khx[s_], keys.khy[s_], (uint32_t)(gb * H + j)));
      float acc = 0.0f;
#pragma unroll 4
      for (int fb = 0; fb < F; fb += 4) {
        float4 y4 = *(const float4*)(yv + fb);
        float w0 = wl[(fb + 0) * 256 + ((jq ^ ((fb + 0) & 7)) << 2) + jm];
        float w1 = wl[(fb + 1) * 256 + ((jq ^ ((fb + 1) & 7)) << 2) + jm];
        float w2 = wl[(fb + 2) * 256 + ((jq ^ ((fb + 2) & 7)) << 2) + jm];
        float w3 = wl[(fb + 3) * 256 + ((jq ^ ((fb + 3) & 7)) << 2) + jm];
        acc = fmaf(y4.x, w0, acc);
        acc = fmaf(y4.y, w1, acc);
        acc = fmaf(y4.z, w2, acc);
        acc = fmaf(y4.w, w3, acc);
      }
      float p = sigmoid_f32(acc);
      hv[j] = (u < p) ? 1.0f : 0.0f;
    }
    __syncthreads();
    if (tid < F) {
      // mean phase: numpy npyv AVX2 order: 4 accumulators x 8 lanes, FMA;
      // combine (C0+C1)+(C2+C3) lanewise; hsum ((L0+L1)+(L2+L3))+((L4+L5)+(L6+L7)).
      const int sq = tid & 7;
      const float4* wr4 = wl4 + tid * 64;
      const float4* hv4 = (const float4*)hv;
      // next-y normal: independent of the dot; compute early to overlap
      float n = 0.0f;
      if (s_ != MC - 1)
        n = normal_f32(keys.kyx[s_], keys.kyy[s_], (uint32_t)(gb * F + tid));
      float C0[8], C1[8], C2[8], C3[8];
#pragma unroll
      for (int l = 0; l < 8; ++l) { C0[l] = 0.0f; C1[l] = 0.0f; C2[l] = 0.0f; C3[l] = 0.0f; }
      for (int k = 0; k < 8; ++k) {
        int eq = k * 8;  // quad base of the 32-block
        float4 wq[8], hq[8];
#pragma unroll
        for (int qq = 0; qq < 8; ++qq) {
          wq[qq] = wr4[(eq + qq) ^ sq];
          hq[qq] = hv4[eq + qq];
        }
        const float* wv = (const float*)wq;
        const float* hh = (const float*)hq;
#pragma unroll
        for (int l = 0; l < 8; ++l) {
          C0[l] = fmaf(wv[l],      hh[l],      C0[l]);
          C1[l] = fmaf(wv[8 + l],  hh[8 + l],  C1[l]);
          C2[l] = fmaf(wv[16 + l], hh[16 + l], C2[l]);
          C3[l] = fmaf(wv[24 + l], hh[24 + l], C3[l]);
        }
      }
      float L[8];
#pragma unroll
      for (int l = 0; l < 8; ++l) L[l] = (C0[l] + C1[l]) + (C2[l] + C3[l]);
      float S = ((L[0] + L[1]) + (L[2] + L[3])) + ((L[4] + L[5]) + (L[6] + L[7]));
      float d = S / ps[tid];
      float mean = bs[tid] + d;
      if (s_ == MC - 1) {
        outp[(size_t)gb * F + tid] = mean;
      } else {
        float t1 = ss[tid] * n;
        yv[tid] = mean + t1;
      }
    }
    __syncthreads();
  }
}

// ---------------- launcher ----------------
extern "C" void kernel_launch(void* const* d_in, const int* in_sizes, int n_in,
                              void* d_out, int out_size, void* d_ws, size_t ws_size,
                              hipStream_t stream) {
  const float* x      = (const float*)d_in[0];
  const float* W_ih   = (const float*)d_in[1];
  const float* W_hh   = (const float*)d_in[2];
  const float* b_ih   = (const float*)d_in[3];
  const float* b_hh   = (const float*)d_in[4];
  const float* bias_W = (const float*)d_in[5];
  const float* bias_b = (const float*)d_in[6];
  const float* prec_W = (const float*)d_in[7];
  const float* prec_b = (const float*)d_in[8];
  const float* wts_W  = (const float*)d_in[9];
  const float* wts_b  = (const float*)d_in[10];
  float* out = (float*)d_out;

  // workspace (~90 MB f32)
  float* wsf = (float*)d_ws;
  size_t off = 0;
  float* w_g     = wsf + off; off += (size_t)CH * NJ;     // 8.39M
  float* h_a     = wsf + off; off += (size_t)B * U;
  float* h_b     = wsf + off; off += (size_t)B * U;
  float* c_a     = wsf + off; off += (size_t)B * U;
  float* c_b     = wsf + off; off += (size_t)B * U;
  float* biasg_g = wsf + off; off += (size_t)B * F;
  float* precg_g = wsf + off; off += (size_t)B * F;
  float* w4t     = wsf + off; off += (size_t)96 * GU * 4;
  float* biasg   = wsf + off; off += GU;
  float* wts4t   = wsf + off; off += (size_t)64 * NJ * 4; // 8.39M
  float* bp4t    = wsf + off; off += (size_t)64 * 256 * 4;
  (void)ws_size;

  hipMemsetAsync(h_a, 0, (size_t)B * U * sizeof(float), stream);
  hipMemsetAsync(c_a, 0, (size_t)B * U * sizeof(float), stream);

  prep_lstm_w_k<<<(GU * 96 + 255) / 256, 256, 0, stream>>>(W_ih, W_hh, b_ih, b_hh,
                                                           (float4*)w4t, biasg);
  prep_wts_k<<<(NJ * 64) / 256, 256, 0, stream>>>(wts_W, (float4*)wts4t);
  prep_bp_k<<<(256 * 64) / 256, 256, 0, stream>>>(bias_W, prec_W, (float4*)bp4t);

  const float* hi = h_a; const float* ci = c_a;
  float* ho = h_b; float* co = c_b;
  for (int t = 0; t < T; ++t) {
    lstm_step_k<<<dim3(B / BT, 4), 256, 0, stream>>>(
        x, hi, ci, (const float4*)w4t, biasg, ho, co, t);
    const float* th_ = hi; hi = ho; ho = (float*)th_;
    const float* tc_ = ci; ci = co; co = (float*)tc_;
  }
  const float* xh = hi;  // last hidden state (T even -> h_a)

  biasprec_k<<<dim3(B / 64), 256, 0, stream>>>(xh, (const float4*)bp4t,
                                               bias_b, prec_b, biasg_g, precg_g);

  // host-side key derivation, jax_threefry_partitionable convention:
  // split(key, n)[i] = full threefry block of (hi=0, lo=i) under `key`.
  GKeys keys;
  uint32_t k0x, k0y, l0, l1;
  tf2x32(0u, 1u, 0u, 0u, k0x, k0y);   // k0    = foldlike(key(1), 0)
  tf2x32(0u, 1u, 0u, 1u, l0, l1);     // kloop = foldlike(key(1), 1)
  keys.k0x = k0x; keys.k0y = k0y;
  for (int s = 0; s < 32; ++s) {
    uint32_t ksx, ksy;
    tf2x32(l0, l1, 0u, (uint32_t)s, ksx, ksy);
    tf2x32(ksx, ksy, 0u, 0u, keys.khx[s], keys.khy[s]);
    tf2x32(ksx, ksy, 0u, 1u, keys.kyx[s], keys.kyy[s]);
  }

  for (int c = 0; c < B / CH; ++c) {
    gemm_xh_k<<<dim3(CH / 64, NJ / 256), 256, 0, stream>>>(
        xh + (size_t)c * CH * U, (const float4*)wts4t, wts_b, w_g);
    gibbs_k<<<dim3(CH), 256, 0, stream>>>(w_g, biasg_g, precg_g, out, keys, c * CH);
  }
}

// Round 13
// 6991.307 us; speedup vs baseline: 1.2038x; 1.1277x over previous
//
#include <hip/hip_runtime.h>
#include <stdint.h>

// numpy is compiled without fast-math; elementwise ufuncs round mul/add
// separately. Keep hipcc from contracting; dots use explicit fmaf where
// the reference backend (OpenBLAS/einsum-FMA) genuinely fuses.
#pragma clang fp contract(off)

#define B 4096
#define T 64
#define F 128
#define U 256
#define H 256
#define GU 1024   // 4U
#define NJ 32768  // F*H
#define MC 32
#define CH 256    // gibbs/gemm batch chunk
#define BT 32     // lstm batch tile

// ---------------- threefry2x32 (JAX, 20 rounds) ----------------
__host__ __device__ inline void tf2x32(uint32_t k0, uint32_t k1,
                                       uint32_t x0, uint32_t x1,
                                       uint32_t& o0, uint32_t& o1) {
  uint32_t ks2 = k0 ^ k1 ^ 0x1BD11BDAu;
  x0 += k0; x1 += k1;
#define TFR(r) { x0 += x1; x1 = (x1 << r) | (x1 >> (32 - r)); x1 ^= x0; }
  TFR(13) TFR(15) TFR(26) TFR(6)
  x0 += k1;  x1 += ks2 + 1u;
  TFR(17) TFR(29) TFR(16) TFR(24)
  x0 += ks2; x1 += k0 + 2u;
  TFR(13) TFR(15) TFR(26) TFR(6)
  x0 += k0;  x1 += k1 + 3u;
  TFR(17) TFR(29) TFR(16) TFR(24)
  x0 += k1;  x1 += ks2 + 4u;
  TFR(13) TFR(15) TFR(26) TFR(6)
  x0 += ks2; x1 += k0 + 5u;
#undef TFR
  o0 = x0; o1 = x1;
}

// partitionable random_bits(32): block at (hi=0, lo=i), fold o0^o1
__device__ inline uint32_t tf_bits(uint32_t kx, uint32_t ky, uint32_t i) {
  uint32_t o0, o1;
  tf2x32(kx, ky, 0u, i, o0, o1);
  return o0 ^ o1;
}

// exact f32 uniform in [0,1)
__device__ inline float u01_f32(uint32_t bits) {
  return __uint_as_float((bits >> 9) | 0x3F800000u) - 1.0f;
}

// Giles erfinv f32 (numpy port: separate mul/add, libm log1pf)
__device__ inline float erfinv_f32(float x) {
  float w = -log1pf(-(x * x));
  float p;
  if (w < 5.0f) {
    float ww = w - 2.5f;
    p = 2.81022636e-08f;
    p = p * ww + 3.43273939e-07f;
    p = p * ww + (-3.5233877e-06f);
    p = p * ww + (-4.39150654e-06f);
    p = p * ww + 0.00021858087f;
    p = p * ww + (-0.00125372503f);
    p = p * ww + (-0.00417768164f);
    p = p * ww + 0.246640727f;
    p = p * ww + 1.50140941f;
  } else {
    float ww = sqrtf(w) - 3.0f;
    p = -0.000200214257f;
    p = p * ww + 0.000100950558f;
    p = p * ww + 0.00134934322f;
    p = p * ww + (-0.00367342844f);
    p = p * ww + 0.00573950773f;
    p = p * ww + (-0.0076224613f);
    p = p * ww + 0.00943887047f;
    p = p * ww + 1.00167406f;
    p = p * ww + 2.83297682f;
  }
  return p * x;
}

// f32 JAX normal: u = max(lo, u01*2 + lo); sqrt(2,f32) * erfinv(u)
__device__ inline float normal_f32(uint32_t kx, uint32_t ky, uint32_t i) {
  float f = u01_f32(tf_bits(kx, ky, i));
  const float lo = -0.99999994039535522461f;
  float v = f * 2.0f + lo;
  v = fmaxf(lo, v);
  return 1.4142135623730951f * erfinv_f32(v);
}

// np port of jax.nn.sigmoid: 1/(1 + np.exp(-x))
__device__ inline float sigmoid_f32(float x) {
  return 1.0f / (1.0f + expf(-x));
}
// np.logaddexp(x, 0) = max(x,0) + log1p(exp(-|x|))
__device__ inline float softplus_f32(float x) {
  return fmaxf(x, 0.0f) + log1pf(expf(-fabsf(x)));
}

// ---------------- prep kernels: k4-major float4 weight views ----------------
__global__ void prep_lstm_w_k(const float* __restrict__ W_ih, const float* __restrict__ W_hh,
                              const float* __restrict__ b_ih, const float* __restrict__ b_hh,
                              float4* __restrict__ w4t, float* __restrict__ biasg) {
  int idx = blockIdx.x * 256 + threadIdx.x;  // j*96 + k4
  if (idx < GU * 96) {
    int j = idx / 96, k4 = idx - j * 96;
    float v[4];
#pragma unroll
    for (int m = 0; m < 4; ++m) {
      int k = k4 * 4 + m;
      v[m] = (k < F) ? W_ih[(size_t)j * F + k] : W_hh[(size_t)j * U + (k - F)];
    }
    w4t[(size_t)k4 * GU + j] = make_float4(v[0], v[1], v[2], v[3]);
  }
  if (idx < GU) biasg[idx] = b_ih[idx] + b_hh[idx];
}

__global__ void prep_wts_k(const float* __restrict__ wts_W, float4* __restrict__ wts4t) {
  int idx = blockIdx.x * 256 + threadIdx.x;  // idx = j*64 + k4
  if (idx >= NJ * 64) return;
  int j = idx >> 6, k4 = idx & 63;
  const float* r = wts_W + (size_t)j * U + k4 * 4;
  wts4t[(size_t)k4 * NJ + j] = make_float4(r[0], r[1], r[2], r[3]);
}

__global__ void prep_bp_k(const float* __restrict__ bias_W, const float* __restrict__ prec_W,
                          float4* __restrict__ bp4t) {
  int idx = blockIdx.x * 256 + threadIdx.x;  // j*64 + k4, j<256
  if (idx >= 256 * 64) return;
  int j = idx >> 6, k4 = idx & 63;
  const float* r = (j < F) ? (bias_W + (size_t)j * U + k4 * 4)
                           : (prec_W + (size_t)(j - F) * U + k4 * 4);
  bp4t[(size_t)k4 * 256 + j] = make_float4(r[0], r[1], r[2], r[3]);
}

// ---------------- LSTM step f32: 2 u's per thread (VALU-bound balance) ------
// g = (x@Wih.T + h@Whh.T) + bias; same k-seq fmaf chains as the passing
// kernel -- only the work distribution changed (each thread now computes the
// identical chains for two u positions, halving LDS-broadcast per FMA).
__global__ __launch_bounds__(256) void lstm_step_k(
    const float* __restrict__ x, const float* __restrict__ h_in,
    const float* __restrict__ c_in, const float4* __restrict__ w4t,
    const float* __restrict__ biasg, float* __restrict__ h_out,
    float* __restrict__ c_out, int t) {
  __shared__ __align__(16) float xt[BT * 128];   // 16 KB
  __shared__ __align__(16) float ht[BT * 256];   // 32 KB
  const int tid = threadIdx.x;
  const int b0 = blockIdx.x * BT;
  const int uh = blockIdx.y;       // 0..1: u range uh*128 .. uh*128+127
  for (int q = tid; q < BT * 32; q += 256) {
    int row = q >> 5, c4 = q & 31;
    *(float4*)(xt + row * 128 + c4 * 4) =
        *(const float4*)(x + ((size_t)(b0 + row) * T + t) * F + c4 * 4);
  }
  for (int q = tid; q < BT * 64; q += 256) {
    int row = q >> 6, c4 = q & 63;
    *(float4*)(ht + row * 256 + c4 * 4) =
        *(const float4*)(h_in + (size_t)(b0 + row) * U + c4 * 4);
  }
  __syncthreads();
  const int u_loc = tid & 63, bg = tid >> 6;
  const int u0 = uh * 128 + u_loc;
  const int u1 = u0 + 64;
  float accX[4][8][2], accH[4][8][2];
#pragma unroll
  for (int g = 0; g < 4; ++g)
#pragma unroll
    for (int b = 0; b < 8; ++b) {
      accX[g][b][0] = 0.0f; accX[g][b][1] = 0.0f;
      accH[g][b][0] = 0.0f; accH[g][b][1] = 0.0f;
    }

#pragma unroll 2
  for (int k4 = 0; k4 < 32; ++k4) {  // x-dot, k-sequential fmaf
    float4 wf[4][2];
#pragma unroll
    for (int g = 0; g < 4; ++g) {
      wf[g][0] = w4t[(size_t)k4 * GU + g * U + u0];
      wf[g][1] = w4t[(size_t)k4 * GU + g * U + u1];
    }
#pragma unroll
    for (int b = 0; b < 8; ++b) {
      float4 av = *(const float4*)(xt + (bg * 8 + b) * 128 + k4 * 4);
#pragma unroll
      for (int g = 0; g < 4; ++g) {
#pragma unroll
        for (int s = 0; s < 2; ++s) {
          accX[g][b][s] = fmaf(av.x, wf[g][s].x, accX[g][b][s]);
          accX[g][b][s] = fmaf(av.y, wf[g][s].y, accX[g][b][s]);
          accX[g][b][s] = fmaf(av.z, wf[g][s].z, accX[g][b][s]);
          accX[g][b][s] = fmaf(av.w, wf[g][s].w, accX[g][b][s]);
        }
      }
    }
  }
#pragma unroll 2
  for (int k4 = 32; k4 < 96; ++k4) {  // h-dot, k-sequential fmaf
    float4 wf[4][2];
#pragma unroll
    for (int g = 0; g < 4; ++g) {
      wf[g][0] = w4t[(size_t)k4 * GU + g * U + u0];
      wf[g][1] = w4t[(size_t)k4 * GU + g * U + u1];
    }
#pragma unroll
    for (int b = 0; b < 8; ++b) {
      float4 av = *(const float4*)(ht + (bg * 8 + b) * 256 + (k4 - 32) * 4);
#pragma unroll
      for (int g = 0; g < 4; ++g) {
#pragma unroll
        for (int s = 0; s < 2; ++s) {
          accH[g][b][s] = fmaf(av.x, wf[g][s].x, accH[g][b][s]);
          accH[g][b][s] = fmaf(av.y, wf[g][s].y, accH[g][b][s]);
          accH[g][b][s] = fmaf(av.z, wf[g][s].z, accH[g][b][s]);
          accH[g][b][s] = fmaf(av.w, wf[g][s].w, accH[g][b][s]);
        }
      }
    }
  }
#pragma unroll
  for (int s = 0; s < 2; ++s) {
    int u = (s == 0) ? u0 : u1;
    float bi = biasg[u], bf = biasg[U + u], bgg = biasg[2 * U + u], bo = biasg[3 * U + u];
#pragma unroll
    for (int b = 0; b < 8; ++b) {
      size_t gi = (size_t)(b0 + bg * 8 + b) * U + u;
      float c = c_in[gi];
      float g_i = (accX[0][b][s] + accH[0][b][s]) + bi;
      float g_f = (accX[1][b][s] + accH[1][b][s]) + bf;
      float g_g = (accX[2][b][s] + accH[2][b][s]) + bgg;
      float g_o = (accX[3][b][s] + accH[3][b][s]) + bo;
      float t1 = sigmoid_f32(g_f) * c;
      float t2 = sigmoid_f32(g_i) * tanhf(g_g);
      float cn = t1 + t2;
      float hn = sigmoid_f32(g_o) * tanhf(cn);
      c_out[gi] = cn;
      h_out[gi] = hn;
    }
  }
}

// ---------------- weights-head GEMM f32: 8 j x 8 b per thread ---------------
// Same k-seq fmaf chain per output; A-broadcast now feeds 32 FMAs per read.
__global__ __launch_bounds__(256) void gemm_xh_k(
    const float* __restrict__ xh_c, const float4* __restrict__ wts4t,
    const float* __restrict__ wts_b, float* __restrict__ outp) {
  __shared__ __align__(16) float xl[64 * 256];  // 64 KB
  const int tid = threadIdx.x;
  const int b0 = blockIdx.x * 64;
  const int jb = blockIdx.y * 256;
  const int jl = tid & 31, bg = tid >> 5;  // 32 j-lanes x 8 b-groups
  for (int q = tid; q < 64 * 64; q += 256) {
    int row = q >> 6, c4 = q & 63;
    *(float4*)(xl + row * 256 + c4 * 4) =
        *(const float4*)(xh_c + (size_t)(b0 + row) * U + c4 * 4);
  }
  __syncthreads();
  float acc[8][8];  // [q][bb]
#pragma unroll
  for (int q = 0; q < 8; ++q)
#pragma unroll
    for (int bb = 0; bb < 8; ++bb) acc[q][bb] = 0.0f;
#pragma unroll 2
  for (int k4 = 0; k4 < 64; ++k4) {
    float4 wf[8];
#pragma unroll
    for (int q = 0; q < 8; ++q)
      wf[q] = wts4t[(size_t)k4 * NJ + jb + q * 32 + jl];
#pragma unroll
    for (int bb = 0; bb < 8; ++bb) {
      float4 av = *(const float4*)(xl + (bg * 8 + bb) * 256 + k4 * 4);
#pragma unroll
      for (int q = 0; q < 8; ++q) {
        acc[q][bb] = fmaf(av.x, wf[q].x, acc[q][bb]);
        acc[q][bb] = fmaf(av.y, wf[q].y, acc[q][bb]);
        acc[q][bb] = fmaf(av.z, wf[q].z, acc[q][bb]);
        acc[q][bb] = fmaf(av.w, wf[q].w, acc[q][bb]);
      }
    }
  }
#pragma unroll
  for (int q = 0; q < 8; ++q) {
    float bb_j = wts_b[jb + q * 32 + jl];
#pragma unroll
    for (int bb = 0; bb < 8; ++bb)
      outp[(size_t)(b0 + bg * 8 + bb) * NJ + jb + q * 32 + jl] = acc[q][bb] + bb_j;
  }
}

// ---------------- bias & precision heads f32: 16 rows/block -----------------
__global__ __launch_bounds__(256) void biasprec_k(
    const float* __restrict__ xh, const float4* __restrict__ bp4t,
    const float* __restrict__ bias_b, const float* __restrict__ prec_b,
    float* __restrict__ bias_g, float* __restrict__ prec_g) {
  __shared__ __align__(16) float xl[16 * 256];  // 16 KB
  const int tid = threadIdx.x;
  const int b0 = blockIdx.x * 16;
  const int j = tid;
  for (int q = tid; q < 16 * 64; q += 256) {
    int row = q >> 6, c4 = q & 63;
    *(float4*)(xl + row * 256 + c4 * 4) =
        *(const float4*)(xh + (size_t)(b0 + row) * U + c4 * 4);
  }
  __syncthreads();
  float acc[16];
#pragma unroll
  for (int b = 0; b < 16; ++b) acc[b] = 0.0f;
#pragma unroll 2
  for (int k4 = 0; k4 < 64; ++k4) {
    float4 wf = bp4t[(size_t)k4 * 256 + j];
#pragma unroll
    for (int b = 0; b < 16; ++b) {
      float4 av = *(const float4*)(xl + b * 256 + k4 * 4);
      acc[b] = fmaf(av.x, wf.x, acc[b]);
      acc[b] = fmaf(av.y, wf.y, acc[b]);
      acc[b] = fmaf(av.z, wf.z, acc[b]);
      acc[b] = fmaf(av.w, wf.w, acc[b]);
    }
  }
  if (j < F) {
    float bb = bias_b[j];
#pragma unroll
    for (int b = 0; b < 16; ++b)
      bias_g[(size_t)(b0 + b) * F + j] = acc[b] + bb;
  } else {
    float pb = prec_b[j - F];
#pragma unroll
    for (int b = 0; b < 16; ++b)
      prec_g[(size_t)(b0 + b) * F + (j - F)] = softplus_f32(acc[b] + pb) + 1e-6f;
  }
}

// ---------------- Gibbs f32: quad-swizzled LDS, vectorized loads ------------
// (unchanged from the passing round-12 kernel)
struct GKeys {
  uint32_t k0x, k0y;
  uint32_t khx[32], khy[32], kyx[32], kyy[32];
};

__global__ __launch_bounds__(256) void gibbs_k(
    const float* __restrict__ w_g, const float* __restrict__ bias_g,
    const float* __restrict__ prec_g, float* __restrict__ outp, GKeys keys,
    int base) {
  __shared__ __align__(16) float wl[32768];   // 128 KB
  __shared__ __align__(16) float yv[128];
  __shared__ __align__(16) float hv[256];
  __shared__ float bs[128];
  __shared__ float ps[128];
  __shared__ float ss[128];
  const int tid = threadIdx.x;
  const int bloc = blockIdx.x;
  const int gb = base + bloc;
  const float4* src = (const float4*)(w_g + (size_t)bloc * NJ);
  float4* wl4 = (float4*)wl;
  for (int q = tid; q < NJ / 4; q += 256) {
    int f = q >> 6;
    int j4 = q & 63;
    wl4[f * 64 + (j4 ^ (f & 7))] = src[q];
  }
  if (tid < F) {
    float bb = bias_g[(size_t)gb * F + tid];
    float pp = prec_g[(size_t)gb * F + tid];
    bs[tid] = bb; ps[tid] = pp;
    float sd = 1.0f / sqrtf(pp);
    ss[tid] = sd;
    float n = normal_f32(keys.k0x, keys.k0y, (uint32_t)(gb * F + tid));
    float t1 = sd * n;
    yv[tid] = bb + t1;
  }
  __syncthreads();
  for (int s_ = 0; s_ < MC; ++s_) {
    {  // h phase: einsum "bf,bfh->bh" -> sequential FMA over f (order fixed)
      const int j = tid;
      const int jq = j >> 2, jm = j & 3;
      float u = u01_f32(tf_bits(keys.khx[s_], keys.khy[s_], (uint32_t)(gb * H + j)));
      float acc = 0.0f;
#pragma unroll 4
      for (int fb = 0; fb < F; fb += 4) {
        float4 y4 = *(const float4*)(yv + fb);
        float w0 = wl[(fb + 0) * 256 + ((jq ^ ((fb + 0) & 7)) << 2) + jm];
        float w1 = wl[(fb + 1) * 256 + ((jq ^ ((fb + 1) & 7)) << 2) + jm];
        float w2 = wl[(fb + 2) * 256 + ((jq ^ ((fb + 2) & 7)) << 2) + jm];
        float w3 = wl[(fb + 3) * 256 + ((jq ^ ((fb + 3) & 7)) << 2) + jm];
        acc = fmaf(y4.x, w0, acc);
        acc = fmaf(y4.y, w1, acc);
        acc = fmaf(y4.z, w2, acc);
        acc = fmaf(y4.w, w3, acc);
      }
      float p = sigmoid_f32(acc);
      hv[j] = (u < p) ? 1.0f : 0.0f;
    }
    __syncthreads();
    if (tid < F) {
      // mean phase: numpy npyv AVX2 order: 4 accumulators x 8 lanes, FMA;
      // combine (C0+C1)+(C2+C3) lanewise; hsum ((L0+L1)+(L2+L3))+((L4+L5)+(L6+L7)).
      const int sq = tid & 7;
      const float4* wr4 = wl4 + tid * 64;
      const float4* hv4 = (const float4*)hv;
      float n = 0.0f;
      if (s_ != MC - 1)
        n = normal_f32(keys.kyx[s_], keys.kyy[s_], (uint32_t)(gb * F + tid));
      float C0[8], C1[8], C2[8], C3[8];
#pragma unroll
      for (int l = 0; l < 8; ++l) { C0[l] = 0.0f; C1[l] = 0.0f; C2[l] = 0.0f; C3[l] = 0.0f; }
      for (int k = 0; k < 8; ++k) {
        int eq = k * 8;  // quad base of the 32-block
        float4 wq[8], hq[8];
#pragma unroll
        for (int qq = 0; qq < 8; ++qq) {
          wq[qq] = wr4[(eq + qq) ^ sq];
          hq[qq] = hv4[eq + qq];
        }
        const float* wv = (const float*)wq;
        const float* hh = (const float*)hq;
#pragma unroll
        for (int l = 0; l < 8; ++l) {
          C0[l] = fmaf(wv[l],      hh[l],      C0[l]);
          C1[l] = fmaf(wv[8 + l],  hh[8 + l],  C1[l]);
          C2[l] = fmaf(wv[16 + l], hh[16 + l], C2[l]);
          C3[l] = fmaf(wv[24 + l], hh[24 + l], C3[l]);
        }
      }
      float L[8];
#pragma unroll
      for (int l = 0; l < 8; ++l) L[l] = (C0[l] + C1[l]) + (C2[l] + C3[l]);
      float S = ((L[0] + L[1]) + (L[2] + L[3])) + ((L[4] + L[5]) + (L[6] + L[7]));
      float d = S / ps[tid];
      float mean = bs[tid] + d;
      if (s_ == MC - 1) {
        outp[(size_t)gb * F + tid] = mean;
      } else {
        float t1 = ss[tid] * n;
        yv[tid] = mean + t1;
      }
    }
    __syncthreads();
  }
}

// ---------------- launcher ----------------
extern "C" void kernel_launch(void* const* d_in, const int* in_sizes, int n_in,
                              void* d_out, int out_size, void* d_ws, size_t ws_size,
                              hipStream_t stream) {
  const float* x      = (const float*)d_in[0];
  const float* W_ih   = (const float*)d_in[1];
  const float* W_hh   = (const float*)d_in[2];
  const float* b_ih   = (const float*)d_in[3];
  const float* b_hh   = (const float*)d_in[4];
  const float* bias_W = (const float*)d_in[5];
  const float* bias_b = (const float*)d_in[6];
  const float* prec_W = (const float*)d_in[7];
  const float* prec_b = (const float*)d_in[8];
  const float* wts_W  = (const float*)d_in[9];
  const float* wts_b  = (const float*)d_in[10];
  float* out = (float*)d_out;

  // workspace (~90 MB f32)
  float* wsf = (float*)d_ws;
  size_t off = 0;
  float* w_g     = wsf + off; off += (size_t)CH * NJ;     // 8.39M
  float* h_a     = wsf + off; off += (size_t)B * U;
  float* h_b     = wsf + off; off += (size_t)B * U;
  float* c_a     = wsf + off; off += (size_t)B * U;
  float* c_b     = wsf + off; off += (size_t)B * U;
  float* biasg_g = wsf + off; off += (size_t)B * F;
  float* precg_g = wsf + off; off += (size_t)B * F;
  float* w4t     = wsf + off; off += (size_t)96 * GU * 4;
  float* biasg   = wsf + off; off += GU;
  float* wts4t   = wsf + off; off += (size_t)64 * NJ * 4; // 8.39M
  float* bp4t    = wsf + off; off += (size_t)64 * 256 * 4;
  (void)ws_size;

  hipMemsetAsync(h_a, 0, (size_t)B * U * sizeof(float), stream);
  hipMemsetAsync(c_a, 0, (size_t)B * U * sizeof(float), stream);

  prep_lstm_w_k<<<(GU * 96 + 255) / 256, 256, 0, stream>>>(W_ih, W_hh, b_ih, b_hh,
                                                           (float4*)w4t, biasg);
  prep_wts_k<<<(NJ * 64) / 256, 256, 0, stream>>>(wts_W, (float4*)wts4t);
  prep_bp_k<<<(256 * 64) / 256, 256, 0, stream>>>(bias_W, prec_W, (float4*)bp4t);

  const float* hi = h_a; const float* ci = c_a;
  float* ho = h_b; float* co = c_b;
  for (int t = 0; t < T; ++t) {
    lstm_step_k<<<dim3(B / BT, 2), 256, 0, stream>>>(
        x, hi, ci, (const float4*)w4t, biasg, ho, co, t);
    const float* th_ = hi; hi = ho; ho = (float*)th_;
    const float* tc_ = ci; ci = co; co = (float*)tc_;
  }
  const float* xh = hi;  // last hidden state (T even -> h_a)

  biasprec_k<<<dim3(B / 16), 256, 0, stream>>>(xh, (const float4*)bp4t,
                                               bias_b, prec_b, biasg_g, precg_g);

  // host-side key derivation, jax_threefry_partitionable convention:
  // split(key, n)[i] = full threefry block of (hi=0, lo=i) under `key`.
  GKeys keys;
  uint32_t k0x, k0y, l0, l1;
  tf2x32(0u, 1u, 0u, 0u, k0x, k0y);   // k0    = foldlike(key(1), 0)
  tf2x32(0u, 1u, 0u, 1u, l0, l1);     // kloop = foldlike(key(1), 1)
  keys.k0x = k0x; keys.k0y = k0y;
  for (int s = 0; s < 32; ++s) {
    uint32_t ksx, ksy;
    tf2x32(l0, l1, 0u, (uint32_t)s, ksx, ksy);
    tf2x32(ksx, ksy, 0u, 0u, keys.khx[s], keys.khy[s]);
    tf2x32(ksx, ksy, 0u, 1u, keys.kyx[s], keys.kyy[s]);
  }

  for (int c = 0; c < B / CH; ++c) {
    gemm_xh_k<<<dim3(CH / 64, NJ / 256), 256, 0, stream>>>(
        xh + (size_t)c * CH * U, (const float4*)wts4t, wts_b, w_g);
    gibbs_k<<<dim3(CH), 256, 0, stream>>>(w_g, biasg_g, precg_g, out, keys, c * CH);
  }
}

// Round 15
// 6665.733 us; speedup vs baseline: 1.2626x; 1.0488x over previous
//
#include <hip/hip_runtime.h>
#include <stdint.h>

// numpy is compiled without fast-math; elementwise ufuncs round mul/add
// separately. Keep hipcc from contracting; dots use explicit fmaf where
// the reference backend (OpenBLAS/einsum-FMA) genuinely fuses.
#pragma clang fp contract(off)

#define B 4096
#define T 64
#define F 128
#define U 256
#define H 256
#define GU 1024   // 4U
#define NJ 32768  // F*H
#define MC 32
#define CH 256    // gibbs/gemm batch chunk
#define BT 32     // lstm batch tile

typedef float nt_f4 __attribute__((ext_vector_type(4)));  // for NT builtins

// ---------------- threefry2x32 (JAX, 20 rounds) ----------------
__host__ __device__ inline void tf2x32(uint32_t k0, uint32_t k1,
                                       uint32_t x0, uint32_t x1,
                                       uint32_t& o0, uint32_t& o1) {
  uint32_t ks2 = k0 ^ k1 ^ 0x1BD11BDAu;
  x0 += k0; x1 += k1;
#define TFR(r) { x0 += x1; x1 = (x1 << r) | (x1 >> (32 - r)); x1 ^= x0; }
  TFR(13) TFR(15) TFR(26) TFR(6)
  x0 += k1;  x1 += ks2 + 1u;
  TFR(17) TFR(29) TFR(16) TFR(24)
  x0 += ks2; x1 += k0 + 2u;
  TFR(13) TFR(15) TFR(26) TFR(6)
  x0 += k0;  x1 += k1 + 3u;
  TFR(17) TFR(29) TFR(16) TFR(24)
  x0 += k1;  x1 += ks2 + 4u;
  TFR(13) TFR(15) TFR(26) TFR(6)
  x0 += ks2; x1 += k0 + 5u;
#undef TFR
  o0 = x0; o1 = x1;
}

// partitionable random_bits(32): block at (hi=0, lo=i), fold o0^o1
__device__ inline uint32_t tf_bits(uint32_t kx, uint32_t ky, uint32_t i) {
  uint32_t o0, o1;
  tf2x32(kx, ky, 0u, i, o0, o1);
  return o0 ^ o1;
}

// exact f32 uniform in [0,1)
__device__ inline float u01_f32(uint32_t bits) {
  return __uint_as_float((bits >> 9) | 0x3F800000u) - 1.0f;
}

// Giles erfinv f32 (numpy port: separate mul/add, libm log1pf)
__device__ inline float erfinv_f32(float x) {
  float w = -log1pf(-(x * x));
  float p;
  if (w < 5.0f) {
    float ww = w - 2.5f;
    p = 2.81022636e-08f;
    p = p * ww + 3.43273939e-07f;
    p = p * ww + (-3.5233877e-06f);
    p = p * ww + (-4.39150654e-06f);
    p = p * ww + 0.00021858087f;
    p = p * ww + (-0.00125372503f);
    p = p * ww + (-0.00417768164f);
    p = p * ww + 0.246640727f;
    p = p * ww + 1.50140941f;
  } else {
    float ww = sqrtf(w) - 3.0f;
    p = -0.000200214257f;
    p = p * ww + 0.000100950558f;
    p = p * ww + 0.00134934322f;
    p = p * ww + (-0.00367342844f);
    p = p * ww + 0.00573950773f;
    p = p * ww + (-0.0076224613f);
    p = p * ww + 0.00943887047f;
    p = p * ww + 1.00167406f;
    p = p * ww + 2.83297682f;
  }
  return p * x;
}

// f32 JAX normal: u = max(lo, u01*2 + lo); sqrt(2,f32) * erfinv(u)
__device__ inline float normal_f32(uint32_t kx, uint32_t ky, uint32_t i) {
  float f = u01_f32(tf_bits(kx, ky, i));
  const float lo = -0.99999994039535522461f;
  float v = f * 2.0f + lo;
  v = fmaxf(lo, v);
  return 1.4142135623730951f * erfinv_f32(v);
}

// np port of jax.nn.sigmoid: 1/(1 + np.exp(-x))
__device__ inline float sigmoid_f32(float x) {
  return 1.0f / (1.0f + expf(-x));
}
// np.logaddexp(x, 0) = max(x,0) + log1p(exp(-|x|))
__device__ inline float softplus_f32(float x) {
  return fmaxf(x, 0.0f) + log1pf(expf(-fabsf(x)));
}

// ---------------- prep kernels: k4-major float4 weight views ----------------
__global__ void prep_lstm_w_k(const float* __restrict__ W_ih, const float* __restrict__ W_hh,
                              const float* __restrict__ b_ih, const float* __restrict__ b_hh,
                              float4* __restrict__ w4t, float* __restrict__ biasg) {
  int idx = blockIdx.x * 256 + threadIdx.x;  // j*96 + k4
  if (idx < GU * 96) {
    int j = idx / 96, k4 = idx - j * 96;
    float v[4];
#pragma unroll
    for (int m = 0; m < 4; ++m) {
      int k = k4 * 4 + m;
      v[m] = (k < F) ? W_ih[(size_t)j * F + k] : W_hh[(size_t)j * U + (k - F)];
    }
    w4t[(size_t)k4 * GU + j] = make_float4(v[0], v[1], v[2], v[3]);
  }
  if (idx < GU) biasg[idx] = b_ih[idx] + b_hh[idx];
}

__global__ void prep_wts_k(const float* __restrict__ wts_W, float4* __restrict__ wts4t) {
  int idx = blockIdx.x * 256 + threadIdx.x;  // idx = j*64 + k4
  if (idx >= NJ * 64) return;
  int j = idx >> 6, k4 = idx & 63;
  const float* r = wts_W + (size_t)j * U + k4 * 4;
  wts4t[(size_t)k4 * NJ + j] = make_float4(r[0], r[1], r[2], r[3]);
}

__global__ void prep_bp_k(const float* __restrict__ bias_W, const float* __restrict__ prec_W,
                          float4* __restrict__ bp4t) {
  int idx = blockIdx.x * 256 + threadIdx.x;  // j*64 + k4, j<256
  if (idx >= 256 * 64) return;
  int j = idx >> 6, k4 = idx & 63;
  const float* r = (j < F) ? (bias_W + (size_t)j * U + k4 * 4)
                           : (prec_W + (size_t)(j - F) * U + k4 * 4);
  bp4t[(size_t)k4 * 256 + j] = make_float4(r[0], r[1], r[2], r[3]);
}

// ---------------- LSTM step f32: 512 threads, 4 rows x 2 u per thread -------
// Same per-(b,u) k-sequential fmaf chains as the passing kernel; only work
// distribution changed (8 waves/block = 2 waves/SIMD hides L2 load latency).
__global__ __launch_bounds__(512) void lstm_step_k(
    const float* __restrict__ x, const float* __restrict__ h_in,
    const float* __restrict__ c_in, const float4* __restrict__ w4t,
    const float* __restrict__ biasg, float* __restrict__ h_out,
    float* __restrict__ c_out, int t) {
  __shared__ __align__(16) float xt[BT * 128];   // 16 KB
  __shared__ __align__(16) float ht[BT * 256];   // 32 KB
  const int tid = threadIdx.x;
  const int b0 = blockIdx.x * BT;
  const int uh = blockIdx.y;       // 0..1: u range uh*128 .. uh*128+127
  for (int q = tid; q < BT * 32; q += 512) {
    int row = q >> 5, c4 = q & 31;
    *(float4*)(xt + row * 128 + c4 * 4) =
        *(const float4*)(x + ((size_t)(b0 + row) * T + t) * F + c4 * 4);
  }
  for (int q = tid; q < BT * 64; q += 512) {
    int row = q >> 6, c4 = q & 63;
    *(float4*)(ht + row * 256 + c4 * 4) =
        *(const float4*)(h_in + (size_t)(b0 + row) * U + c4 * 4);
  }
  __syncthreads();
  const int u_loc = tid & 63, bg = tid >> 6;   // bg 0..7, 4 rows each
  const int u0 = uh * 128 + u_loc;
  const int u1 = u0 + 64;
  float accX[4][4][2], accH[4][4][2];
#pragma unroll
  for (int g = 0; g < 4; ++g)
#pragma unroll
    for (int b = 0; b < 4; ++b) {
      accX[g][b][0] = 0.0f; accX[g][b][1] = 0.0f;
      accH[g][b][0] = 0.0f; accH[g][b][1] = 0.0f;
    }

#pragma unroll 2
  for (int k4 = 0; k4 < 32; ++k4) {  // x-dot, k-sequential fmaf
    float4 wf[4][2];
#pragma unroll
    for (int g = 0; g < 4; ++g) {
      wf[g][0] = w4t[(size_t)k4 * GU + g * U + u0];
      wf[g][1] = w4t[(size_t)k4 * GU + g * U + u1];
    }
#pragma unroll
    for (int b = 0; b < 4; ++b) {
      float4 av = *(const float4*)(xt + (bg * 4 + b) * 128 + k4 * 4);
#pragma unroll
      for (int g = 0; g < 4; ++g) {
#pragma unroll
        for (int s = 0; s < 2; ++s) {
          accX[g][b][s] = fmaf(av.x, wf[g][s].x, accX[g][b][s]);
          accX[g][b][s] = fmaf(av.y, wf[g][s].y, accX[g][b][s]);
          accX[g][b][s] = fmaf(av.z, wf[g][s].z, accX[g][b][s]);
          accX[g][b][s] = fmaf(av.w, wf[g][s].w, accX[g][b][s]);
        }
      }
    }
  }
#pragma unroll 2
  for (int k4 = 32; k4 < 96; ++k4) {  // h-dot, k-sequential fmaf
    float4 wf[4][2];
#pragma unroll
    for (int g = 0; g < 4; ++g) {
      wf[g][0] = w4t[(size_t)k4 * GU + g * U + u0];
      wf[g][1] = w4t[(size_t)k4 * GU + g * U + u1];
    }
#pragma unroll
    for (int b = 0; b < 4; ++b) {
      float4 av = *(const float4*)(ht + (bg * 4 + b) * 256 + (k4 - 32) * 4);
#pragma unroll
      for (int g = 0; g < 4; ++g) {
#pragma unroll
        for (int s = 0; s < 2; ++s) {
          accH[g][b][s] = fmaf(av.x, wf[g][s].x, accH[g][b][s]);
          accH[g][b][s] = fmaf(av.y, wf[g][s].y, accH[g][b][s]);
          accH[g][b][s] = fmaf(av.z, wf[g][s].z, accH[g][b][s]);
          accH[g][b][s] = fmaf(av.w, wf[g][s].w, accH[g][b][s]);
        }
      }
    }
  }
#pragma unroll
  for (int s = 0; s < 2; ++s) {
    int u = (s == 0) ? u0 : u1;
    float bi = biasg[u], bf = biasg[U + u], bgg = biasg[2 * U + u], bo = biasg[3 * U + u];
#pragma unroll
    for (int b = 0; b < 4; ++b) {
      size_t gi = (size_t)(b0 + bg * 4 + b) * U + u;
      float c = c_in[gi];
      float g_i = (accX[0][b][s] + accH[0][b][s]) + bi;
      float g_f = (accX[1][b][s] + accH[1][b][s]) + bf;
      float g_g = (accX[2][b][s] + accH[2][b][s]) + bgg;
      float g_o = (accX[3][b][s] + accH[3][b][s]) + bo;
      float t1 = sigmoid_f32(g_f) * c;
      float t2 = sigmoid_f32(g_i) * tanhf(g_g);
      float cn = t1 + t2;
      float hn = sigmoid_f32(g_o) * tanhf(cn);
      c_out[gi] = cn;
      h_out[gi] = hn;
    }
  }
}

// ---------------- weights-head GEMM f32: 8 j x 8 b per thread ---------------
// Same k-seq fmaf chain per output; w_g written with nontemporal stores so
// wts4t stays L2/L3-resident across chunks.
__global__ __launch_bounds__(256) void gemm_xh_k(
    const float* __restrict__ xh_c, const float4* __restrict__ wts4t,
    const float* __restrict__ wts_b, float* __restrict__ outp) {
  __shared__ __align__(16) float xl[64 * 256];  // 64 KB
  const int tid = threadIdx.x;
  const int b0 = blockIdx.x * 64;
  const int jb = blockIdx.y * 256;
  const int jl = tid & 31, bg = tid >> 5;  // 32 j-lanes x 8 b-groups
  for (int q = tid; q < 64 * 64; q += 256) {
    int row = q >> 6, c4 = q & 63;
    *(float4*)(xl + row * 256 + c4 * 4) =
        *(const float4*)(xh_c + (size_t)(b0 + row) * U + c4 * 4);
  }
  __syncthreads();
  float acc[8][8];  // [q][bb]
#pragma unroll
  for (int q = 0; q < 8; ++q)
#pragma unroll
    for (int bb = 0; bb < 8; ++bb) acc[q][bb] = 0.0f;
#pragma unroll 2
  for (int k4 = 0; k4 < 64; ++k4) {
    float4 wf[8];
#pragma unroll
    for (int q = 0; q < 8; ++q)
      wf[q] = wts4t[(size_t)k4 * NJ + jb + q * 32 + jl];
#pragma unroll
    for (int bb = 0; bb < 8; ++bb) {
      float4 av = *(const float4*)(xl + (bg * 8 + bb) * 256 + k4 * 4);
#pragma unroll
      for (int q = 0; q < 8; ++q) {
        acc[q][bb] = fmaf(av.x, wf[q].x, acc[q][bb]);
        acc[q][bb] = fmaf(av.y, wf[q].y, acc[q][bb]);
        acc[q][bb] = fmaf(av.z, wf[q].z, acc[q][bb]);
        acc[q][bb] = fmaf(av.w, wf[q].w, acc[q][bb]);
      }
    }
  }
#pragma unroll
  for (int q = 0; q < 8; ++q) {
    float bb_j = wts_b[jb + q * 32 + jl];
#pragma unroll
    for (int bb = 0; bb < 8; ++bb)
      __builtin_nontemporal_store(acc[q][bb] + bb_j,
          &outp[(size_t)(b0 + bg * 8 + bb) * NJ + jb + q * 32 + jl]);
  }
}

// ---------------- bias & precision heads f32: 16 rows/block -----------------
__global__ __launch_bounds__(256) void biasprec_k(
    const float* __restrict__ xh, const float4* __restrict__ bp4t,
    const float* __restrict__ bias_b, const float* __restrict__ prec_b,
    float* __restrict__ bias_g, float* __restrict__ prec_g) {
  __shared__ __align__(16) float xl[16 * 256];  // 16 KB
  const int tid = threadIdx.x;
  const int b0 = blockIdx.x * 16;
  const int j = tid;
  for (int q = tid; q < 16 * 64; q += 256) {
    int row = q >> 6, c4 = q & 63;
    *(float4*)(xl + row * 256 + c4 * 4) =
        *(const float4*)(xh + (size_t)(b0 + row) * U + c4 * 4);
  }
  __syncthreads();
  float acc[16];
#pragma unroll
  for (int b = 0; b < 16; ++b) acc[b] = 0.0f;
#pragma unroll 2
  for (int k4 = 0; k4 < 64; ++k4) {
    float4 wf = bp4t[(size_t)k4 * 256 + j];
#pragma unroll
    for (int b = 0; b < 16; ++b) {
      float4 av = *(const float4*)(xl + b * 256 + k4 * 4);
      acc[b] = fmaf(av.x, wf.x, acc[b]);
      acc[b] = fmaf(av.y, wf.y, acc[b]);
      acc[b] = fmaf(av.z, wf.z, acc[b]);
      acc[b] = fmaf(av.w, wf.w, acc[b]);
    }
  }
  if (j < F) {
    float bb = bias_b[j];
#pragma unroll
    for (int b = 0; b < 16; ++b)
      bias_g[(size_t)(b0 + b) * F + j] = acc[b] + bb;
  } else {
    float pb = prec_b[j - F];
#pragma unroll
    for (int b = 0; b < 16; ++b)
      prec_g[(size_t)(b0 + b) * F + (j - F)] = softplus_f32(acc[b] + pb) + 1e-6f;
  }
}

// ---------------- Gibbs f32: 512-thread staging, quad-swizzled LDS ----------
// Staging: 8 waves, 16 independent NT loads per thread issued before any LDS
// write (deep memory pipeline). LDS layout identical to the passing kernel:
// wl4[p] = src[(p>>6)*64 + ((p&63) ^ ((p>>6)&7))]  (XOR is involutive).
// Compute phases (tid<256 / tid<128) byte-identical to the passing kernel.
struct GKeys {
  uint32_t k0x, k0y;
  uint32_t khx[32], khy[32], kyx[32], kyy[32];
};

__global__ __launch_bounds__(512) void gibbs_k(
    const float* __restrict__ w_g, const float* __restrict__ bias_g,
    const float* __restrict__ prec_g, float* __restrict__ outp, GKeys keys,
    int base) {
  __shared__ __align__(16) float wl[32768];   // 128 KB
  __shared__ __align__(16) float yv[128];
  __shared__ __align__(16) float hv[256];
  __shared__ float bs[128];
  __shared__ float ps[128];
  __shared__ float ss[128];
  const int tid = threadIdx.x;
  const int bloc = blockIdx.x;
  const int gb = base + bloc;
  const nt_f4* src = (const nt_f4*)(w_g + (size_t)bloc * NJ);
  float4* wl4 = (float4*)wl;
  {
    nt_f4 stg[16];
#pragma unroll
    for (int i = 0; i < 16; ++i) {
      int p = tid + i * 512;
      int f = p >> 6, j4 = p & 63;
      stg[i] = __builtin_nontemporal_load(&src[f * 64 + (j4 ^ (f & 7))]);
    }
#pragma unroll
    for (int i = 0; i < 16; ++i)
      *(nt_f4*)(&wl4[tid + i * 512]) = stg[i];
  }
  if (tid < F) {
    float bb = bias_g[(size_t)gb * F + tid];
    float pp = prec_g[(size_t)gb * F + tid];
    bs[tid] = bb; ps[tid] = pp;
    float sd = 1.0f / sqrtf(pp);
    ss[tid] = sd;
    float n = normal_f32(keys.k0x, keys.k0y, (uint32_t)(gb * F + tid));
    float t1 = sd * n;
    yv[tid] = bb + t1;
  }
  __syncthreads();
  for (int s_ = 0; s_ < MC; ++s_) {
    if (tid < H) {  // h phase: einsum "bf,bfh->bh" -> sequential FMA over f
      const int j = tid;
      const int jq = j >> 2, jm = j & 3;
      float u = u01_f32(tf_bits(keys.khx[s_], keys.khy[s_], (uint32_t)(gb * H + j)));
      float acc = 0.0f;
#pragma unroll 4
      for (int fb = 0; fb < F; fb += 4) {
        float4 y4 = *(const float4*)(yv + fb);
        float w0 = wl[(fb + 0) * 256 + ((jq ^ ((fb + 0) & 7)) << 2) + jm];
        float w1 = wl[(fb + 1) * 256 + ((jq ^ ((fb + 1) & 7)) << 2) + jm];
        float w2 = wl[(fb + 2) * 256 + ((jq ^ ((fb + 2) & 7)) << 2) + jm];
        float w3 = wl[(fb + 3) * 256 + ((jq ^ ((fb + 3) & 7)) << 2) + jm];
        acc = fmaf(y4.x, w0, acc);
        acc = fmaf(y4.y, w1, acc);
        acc = fmaf(y4.z, w2, acc);
        acc = fmaf(y4.w, w3, acc);
      }
      float p = sigmoid_f32(acc);
      hv[j] = (u < p) ? 1.0f : 0.0f;
    }
    __syncthreads();
    if (tid < F) {
      // mean phase: numpy npyv AVX2 order: 4 accumulators x 8 lanes, FMA;
      // combine (C0+C1)+(C2+C3) lanewise; hsum ((L0+L1)+(L2+L3))+((L4+L5)+(L6+L7)).
      const int sq = tid & 7;
      const float4* wr4 = wl4 + tid * 64;
      const float4* hv4 = (const float4*)hv;
      float n = 0.0f;
      if (s_ != MC - 1)
        n = normal_f32(keys.kyx[s_], keys.kyy[s_], (uint32_t)(gb * F + tid));
      float C0[8], C1[8], C2[8], C3[8];
#pragma unroll
      for (int l = 0; l < 8; ++l) { C0[l] = 0.0f; C1[l] = 0.0f; C2[l] = 0.0f; C3[l] = 0.0f; }
      for (int k = 0; k < 8; ++k) {
        int eq = k * 8;  // quad base of the 32-block
        float4 wq[8], hq[8];
#pragma unroll
        for (int qq = 0; qq < 8; ++qq) {
          wq[qq] = wr4[(eq + qq) ^ sq];
          hq[qq] = hv4[eq + qq];
        }
        const float* wv = (const float*)wq;
        const float* hh = (const float*)hq;
#pragma unroll
        for (int l = 0; l < 8; ++l) {
          C0[l] = fmaf(wv[l],      hh[l],      C0[l]);
          C1[l] = fmaf(wv[8 + l],  hh[8 + l],  C1[l]);
          C2[l] = fmaf(wv[16 + l], hh[16 + l], C2[l]);
          C3[l] = fmaf(wv[24 + l], hh[24 + l], C3[l]);
        }
      }
      float L[8];
#pragma unroll
      for (int l = 0; l < 8; ++l) L[l] = (C0[l] + C1[l]) + (C2[l] + C3[l]);
      float S = ((L[0] + L[1]) + (L[2] + L[3])) + ((L[4] + L[5]) + (L[6] + L[7]));
      float d = S / ps[tid];
      float mean = bs[tid] + d;
      if (s_ == MC - 1) {
        outp[(size_t)gb * F + tid] = mean;
      } else {
        float t1 = ss[tid] * n;
        yv[tid] = mean + t1;
      }
    }
    __syncthreads();
  }
}

// ---------------- launcher ----------------
extern "C" void kernel_launch(void* const* d_in, const int* in_sizes, int n_in,
                              void* d_out, int out_size, void* d_ws, size_t ws_size,
                              hipStream_t stream) {
  const float* x      = (const float*)d_in[0];
  const float* W_ih   = (const float*)d_in[1];
  const float* W_hh   = (const float*)d_in[2];
  const float* b_ih   = (const float*)d_in[3];
  const float* b_hh   = (const float*)d_in[4];
  const float* bias_W = (const float*)d_in[5];
  const float* bias_b = (const float*)d_in[6];
  const float* prec_W = (const float*)d_in[7];
  const float* prec_b = (const float*)d_in[8];
  const float* wts_W  = (const float*)d_in[9];
  const float* wts_b  = (const float*)d_in[10];
  float* out = (float*)d_out;

  // workspace (~90 MB f32)
  float* wsf = (float*)d_ws;
  size_t off = 0;
  float* w_g     = wsf + off; off += (size_t)CH * NJ;     // 8.39M
  float* h_a     = wsf + off; off += (size_t)B * U;
  float* h_b     = wsf + off; off += (size_t)B * U;
  float* c_a     = wsf + off; off += (size_t)B * U;
  float* c_b     = wsf + off; off += (size_t)B * U;
  float* biasg_g = wsf + off; off += (size_t)B * F;
  float* precg_g = wsf + off; off += (size_t)B * F;
  float* w4t     = wsf + off; off += (size_t)96 * GU * 4;
  float* biasg   = wsf + off; off += GU;
  float* wts4t   = wsf + off; off += (size_t)64 * NJ * 4; // 8.39M
  float* bp4t    = wsf + off; off += (size_t)64 * 256 * 4;
  (void)ws_size;

  (void)hipMemsetAsync(h_a, 0, (size_t)B * U * sizeof(float), stream);
  (void)hipMemsetAsync(c_a, 0, (size_t)B * U * sizeof(float), stream);

  prep_lstm_w_k<<<(GU * 96 + 255) / 256, 256, 0, stream>>>(W_ih, W_hh, b_ih, b_hh,
                                                           (float4*)w4t, biasg);
  prep_wts_k<<<(NJ * 64) / 256, 256, 0, stream>>>(wts_W, (float4*)wts4t);
  prep_bp_k<<<(256 * 64) / 256, 256, 0, stream>>>(bias_W, prec_W, (float4*)bp4t);

  const float* hi = h_a; const float* ci = c_a;
  float* ho = h_b; float* co = c_b;
  for (int t = 0; t < T; ++t) {
    lstm_step_k<<<dim3(B / BT, 2), 512, 0, stream>>>(
        x, hi, ci, (const float4*)w4t, biasg, ho, co, t);
    const float* th_ = hi; hi = ho; ho = (float*)th_;
    const float* tc_ = ci; ci = co; co = (float*)tc_;
  }
  const float* xh = hi;  // last hidden state (T even -> h_a)

  biasprec_k<<<dim3(B / 16), 256, 0, stream>>>(xh, (const float4*)bp4t,
                                               bias_b, prec_b, biasg_g, precg_g);

  // host-side key derivation, jax_threefry_partitionable convention:
  // split(key, n)[i] = full threefry block of (hi=0, lo=i) under `key`.
  GKeys keys;
  uint32_t k0x, k0y, l0, l1;
  tf2x32(0u, 1u, 0u, 0u, k0x, k0y);   // k0    = foldlike(key(1), 0)
  tf2x32(0u, 1u, 0u, 1u, l0, l1);     // kloop = foldlike(key(1), 1)
  keys.k0x = k0x; keys.k0y = k0y;
  for (int s = 0; s < 32; ++s) {
    uint32_t ksx, ksy;
    tf2x32(l0, l1, 0u, (uint32_t)s, ksx, ksy);
    tf2x32(ksx, ksy, 0u, 0u, keys.khx[s], keys.khy[s]);
    tf2x32(ksx, ksy, 0u, 1u, keys.kyx[s], keys.kyy[s]);
  }

  for (int c = 0; c < B / CH; ++c) {
    gemm_xh_k<<<dim3(CH / 64, NJ / 256), 256, 0, stream>>>(
        xh + (size_t)c * CH * U, (const float4*)wts4t, wts_b, w_g);
    gibbs_k<<<dim3(CH), 512, 0, stream>>>(w_g, biasg_g, precg_g, out, keys, c * CH);
  }
}